// Round 1
// baseline (16679.720 us; speedup 1.0000x reference)
//
#include <hip/hip_runtime.h>
#include <hip/hip_bf16.h>

#define D 64
#define NEG_SLOPE 0.2f
#define EPS 1e-12f

// ---------------------------------------------------------------------------
// SpMM scatter: side[rows[e]] += vals[e] * ego[cols[e]]
// 16 lanes per edge, each lane handles a float4 (16 lanes * 4 = 64 cols).
// ---------------------------------------------------------------------------
__global__ __launch_bounds__(256) void scatter_spmm(
    const int* __restrict__ rows, const int* __restrict__ cols,
    const float* __restrict__ vals, const float* __restrict__ ego,
    float* __restrict__ side, int nnz) {
  long long t = (long long)blockIdx.x * blockDim.x + threadIdx.x;
  int e = (int)(t >> 4);
  if (e >= nnz) return;
  int c4 = (int)(t & 15);
  int r = rows[e];
  int c = cols[e];
  float v = vals[e];
  const float4* src = (const float4*)(ego + (size_t)c * D);
  float4 x = src[c4];
  float* dst = side + (size_t)r * D + c4 * 4;
  atomicAdd(dst + 0, v * x.x);
  atomicAdd(dst + 1, v * x.y);
  atomicAdd(dst + 2, v * x.z);
  atomicAdd(dst + 3, v * x.w);
}

// ---------------------------------------------------------------------------
// Per-node transform: ego[n] = leaky_relu(side[n]@Wgc + bgc + (ego[n]*side[n])@Wbi + bbi)
// One wave per node (lane = output column). W matrices staged in LDS.
// ---------------------------------------------------------------------------
__global__ __launch_bounds__(256) void transform_nodes(
    float* __restrict__ ego, const float* __restrict__ side,
    const float* __restrict__ Wgc, const float* __restrict__ bgc,
    const float* __restrict__ Wbi, const float* __restrict__ bbi, int N) {
  __shared__ float sWgc[D * D];
  __shared__ float sWbi[D * D];
  __shared__ float sb[2 * D];
  __shared__ float sS[4][D];
  __shared__ float sP[4][D];

  for (int idx = threadIdx.x; idx < D * D; idx += 256) {
    sWgc[idx] = Wgc[idx];
    sWbi[idx] = Wbi[idx];
  }
  if (threadIdx.x < D) {
    sb[threadIdx.x] = bgc[threadIdx.x];
    sb[D + threadIdx.x] = bbi[threadIdx.x];
  }
  __syncthreads();

  int wave = threadIdx.x >> 6;
  int lane = threadIdx.x & 63;
  int waveGlobal = blockIdx.x * 4 + wave;
  int nWaves = gridDim.x * 4;

  for (int n = waveGlobal; n < N; n += nWaves) {
    float s = side[(size_t)n * D + lane];
    float e = ego[(size_t)n * D + lane];
    sS[wave][lane] = s;
    sP[wave][lane] = e * s;
    // wave-synchronous: same wave wrote, compiler inserts lgkmcnt waits
    float accg = sb[lane];
    float accb = sb[D + lane];
#pragma unroll
    for (int i = 0; i < D; i++) {
      float si = sS[wave][i];   // LDS broadcast
      float pi = sP[wave][i];   // LDS broadcast
      accg = fmaf(si, sWgc[i * D + lane], accg);
      accb = fmaf(pi, sWbi[i * D + lane], accb);
    }
    float val = accg + accb;
    val = val > 0.f ? val : NEG_SLOPE * val;
    ego[(size_t)n * D + lane] = val;
  }
}

// ---------------------------------------------------------------------------
// Gather one 64-wide slice of the three outputs straight into d_out.
// One wave per output row; optional per-row L2 normalization (wave reduce).
// ---------------------------------------------------------------------------
__global__ __launch_bounds__(256) void gather_out(
    const float* __restrict__ ego, const int* __restrict__ u,
    const int* __restrict__ iidx, const int* __restrict__ jidx,
    float* __restrict__ out, int n_users, int B, int slice, int normalize) {
  int r = blockIdx.x * 4 + (threadIdx.x >> 6);
  int lane = threadIdx.x & 63;
  if (r >= 3 * B) return;
  int which = r / B;
  int b = r - which * B;
  int n = (which == 0) ? u[b] : (n_users + ((which == 1) ? iidx[b] : jidx[b]));
  float v = ego[(size_t)n * D + lane];
  if (normalize) {
    float sq = v * v;
#pragma unroll
    for (int off = 32; off > 0; off >>= 1) sq += __shfl_xor(sq, off);
    float norm = sqrtf(sq);
    v = v / fmaxf(norm, EPS);
  }
  out[(size_t)which * B * 256 + (size_t)b * 256 + slice * D + lane] = v;
}

extern "C" void kernel_launch(void* const* d_in, const int* in_sizes, int n_in,
                              void* d_out, int out_size, void* d_ws, size_t ws_size,
                              hipStream_t stream) {
  const int*   rows     = (const int*)d_in[0];
  const int*   cols     = (const int*)d_in[1];
  const float* vals     = (const float*)d_in[2];
  const float* user_emb = (const float*)d_in[3];
  const float* item_emb = (const float*)d_in[4];
  const float* W_gc     = (const float*)d_in[5];  // (3,64,64)
  const float* b_gc     = (const float*)d_in[6];  // (3,1,64)
  const float* W_bi     = (const float*)d_in[7];
  const float* b_bi     = (const float*)d_in[8];
  const int*   u        = (const int*)d_in[9];
  const int*   iidx     = (const int*)d_in[10];
  const int*   jidx     = (const int*)d_in[11];

  int nnz     = in_sizes[0];
  int n_users = in_sizes[3] / D;
  int n_items = in_sizes[4] / D;
  int N       = n_users + n_items;
  int B       = in_sizes[9];
  float* out  = (float*)d_out;

  float* ego  = (float*)d_ws;              // N*64 floats
  float* side = ego + (size_t)N * D;       // N*64 floats

  // ego = concat(user_emb, item_emb)
  hipMemcpyAsync(ego, user_emb, (size_t)n_users * D * sizeof(float),
                 hipMemcpyDeviceToDevice, stream);
  hipMemcpyAsync(ego + (size_t)n_users * D, item_emb,
                 (size_t)n_items * D * sizeof(float),
                 hipMemcpyDeviceToDevice, stream);

  // slice 0: raw embeddings (un-normalized)
  {
    int gblocks = (3 * B + 3) / 4;
    gather_out<<<gblocks, 256, 0, stream>>>(ego, u, iidx, jidx, out, n_users, B,
                                            0, 0);
  }

  long long sthreads = (long long)nnz * 16;
  int sblocks = (int)((sthreads + 255) / 256);

  for (int k = 0; k < 3; k++) {
    hipMemsetAsync(side, 0, (size_t)N * D * sizeof(float), stream);
    scatter_spmm<<<sblocks, 256, 0, stream>>>(rows, cols, vals, ego, side, nnz);
    transform_nodes<<<2048, 256, 0, stream>>>(
        ego, side, W_gc + (size_t)k * D * D, b_gc + (size_t)k * D,
        W_bi + (size_t)k * D * D, b_bi + (size_t)k * D, N);
    int gblocks = (3 * B + 3) / 4;
    gather_out<<<gblocks, 256, 0, stream>>>(ego, u, iidx, jidx, out, n_users, B,
                                            k + 1, 1);
  }
}

// Round 2
// 1983.568 us; speedup vs baseline: 8.4089x; 8.4089x over previous
//
#include <hip/hip_runtime.h>
#include <hip/hip_bf16.h>

#define D 64
#define NEG_SLOPE 0.2f
#define EPS 1e-12f

// ===========================================================================
// CSR build: histogram -> hierarchical exclusive scan -> stable-ish fill
// ===========================================================================

__global__ __launch_bounds__(256) void hist_rows(const int* __restrict__ rows,
                                                 int* __restrict__ counts,
                                                 int nnz) {
  int e = blockIdx.x * 256 + threadIdx.x;
  if (e < nnz) atomicAdd(&counts[rows[e]], 1);
}

// Block scans 1024 counts (256 thr x 4), writes per-element exclusive prefix
// (block-local) into row_ptr and the block total into partials[blockIdx.x].
#define SCAN_E 4
__global__ __launch_bounds__(256) void scan_local(const int* __restrict__ counts,
                                                  int* __restrict__ row_ptr,
                                                  int* __restrict__ partials,
                                                  int N) {
  __shared__ int sums[256];
  int base = blockIdx.x * (256 * SCAN_E) + threadIdx.x * SCAN_E;
  int c[SCAN_E];
  int tsum = 0;
#pragma unroll
  for (int i = 0; i < SCAN_E; i++) {
    int idx = base + i;
    c[i] = (idx < N) ? counts[idx] : 0;
    tsum += c[i];
  }
  sums[threadIdx.x] = tsum;
  __syncthreads();
  for (int off = 1; off < 256; off <<= 1) {
    int t = (threadIdx.x >= off) ? sums[threadIdx.x - off] : 0;
    __syncthreads();
    sums[threadIdx.x] += t;
    __syncthreads();
  }
  int run = sums[threadIdx.x] - tsum;  // exclusive offset for this thread
#pragma unroll
  for (int i = 0; i < SCAN_E; i++) {
    int idx = base + i;
    if (idx < N) row_ptr[idx] = run;
    run += c[i];
  }
  if (threadIdx.x == 255) partials[blockIdx.x] = sums[255];
}

// Single block: exclusive scan of up to 1024 partials, in place.
__global__ __launch_bounds__(256) void scan_partials(int* __restrict__ partials,
                                                     int nparts) {
  __shared__ int sums[256];
  int base = threadIdx.x * SCAN_E;
  int c[SCAN_E];
  int tsum = 0;
#pragma unroll
  for (int i = 0; i < SCAN_E; i++) {
    int idx = base + i;
    c[i] = (idx < nparts) ? partials[idx] : 0;
    tsum += c[i];
  }
  sums[threadIdx.x] = tsum;
  __syncthreads();
  for (int off = 1; off < 256; off <<= 1) {
    int t = (threadIdx.x >= off) ? sums[threadIdx.x - off] : 0;
    __syncthreads();
    sums[threadIdx.x] += t;
    __syncthreads();
  }
  int run = sums[threadIdx.x] - tsum;
#pragma unroll
  for (int i = 0; i < SCAN_E; i++) {
    int idx = base + i;
    if (idx < nparts) partials[idx] = run;
    run += c[i];
  }
}

__global__ __launch_bounds__(256) void add_offsets(int* __restrict__ row_ptr,
                                                   const int* __restrict__ partials,
                                                   int N, int nnz) {
  int i = blockIdx.x * 256 + threadIdx.x;
  if (i == 0) row_ptr[N] = nnz;
  if (i < N) row_ptr[i] += partials[i >> 10];
}

// Packed fill: pairs[pos] = (col, val-bits)
__global__ __launch_bounds__(256) void fill_csr_packed(
    const int* __restrict__ rows, const int* __restrict__ cols,
    const float* __restrict__ vals, int* __restrict__ cursor,
    int2* __restrict__ pairs, int nnz) {
  int e = blockIdx.x * 256 + threadIdx.x;
  if (e >= nnz) return;
  int r = rows[e];
  int pos = atomicAdd(&cursor[r], 1);
  pairs[pos] = make_int2(cols[e], __float_as_int(vals[e]));
}

// Indirect fill: eids[pos] = e
__global__ __launch_bounds__(256) void fill_csr_eid(
    const int* __restrict__ rows, int* __restrict__ cursor,
    int* __restrict__ eids, int nnz) {
  int e = blockIdx.x * 256 + threadIdx.x;
  if (e >= nnz) return;
  int r = rows[e];
  int pos = atomicAdd(&cursor[r], 1);
  eids[pos] = e;
}

// ===========================================================================
// SpMM gather: one wave per row, lane = column, register accumulate.
// ===========================================================================

__global__ __launch_bounds__(256) void spmm_gather_packed(
    const int* __restrict__ row_ptr, const int2* __restrict__ pairs,
    const float* __restrict__ ego, float* __restrict__ side, int N) {
  int wave = threadIdx.x >> 6;
  int lane = threadIdx.x & 63;
  int w = blockIdx.x * 4 + wave;
  int stride = gridDim.x * 4;
  for (int n = w; n < N; n += stride) {
    int s = row_ptr[n];
    int e = row_ptr[n + 1];
    float acc = 0.f;
    int k = s;
    for (; k + 3 < e; k += 4) {
      int2 p0 = pairs[k], p1 = pairs[k + 1], p2 = pairs[k + 2], p3 = pairs[k + 3];
      float x0 = ego[(size_t)p0.x * D + lane];
      float x1 = ego[(size_t)p1.x * D + lane];
      float x2 = ego[(size_t)p2.x * D + lane];
      float x3 = ego[(size_t)p3.x * D + lane];
      acc = fmaf(__int_as_float(p0.y), x0, acc);
      acc = fmaf(__int_as_float(p1.y), x1, acc);
      acc = fmaf(__int_as_float(p2.y), x2, acc);
      acc = fmaf(__int_as_float(p3.y), x3, acc);
    }
    for (; k < e; k++) {
      int2 p = pairs[k];
      acc = fmaf(__int_as_float(p.y), ego[(size_t)p.x * D + lane], acc);
    }
    side[(size_t)n * D + lane] = acc;
  }
}

__global__ __launch_bounds__(256) void spmm_gather_eid(
    const int* __restrict__ row_ptr, const int* __restrict__ eids,
    const int* __restrict__ cols, const float* __restrict__ vals,
    const float* __restrict__ ego, float* __restrict__ side, int N) {
  int wave = threadIdx.x >> 6;
  int lane = threadIdx.x & 63;
  int w = blockIdx.x * 4 + wave;
  int stride = gridDim.x * 4;
  for (int n = w; n < N; n += stride) {
    int s = row_ptr[n];
    int e = row_ptr[n + 1];
    float acc = 0.f;
    int k = s;
    for (; k + 1 < e; k += 2) {
      int e0 = eids[k], e1 = eids[k + 1];
      int c0 = cols[e0], c1 = cols[e1];
      float v0 = vals[e0], v1 = vals[e1];
      acc = fmaf(v0, ego[(size_t)c0 * D + lane], acc);
      acc = fmaf(v1, ego[(size_t)c1 * D + lane], acc);
    }
    for (; k < e; k++) {
      int e0 = eids[k];
      acc = fmaf(vals[e0], ego[(size_t)cols[e0] * D + lane], acc);
    }
    side[(size_t)n * D + lane] = acc;
  }
}

// ===========================================================================
// Fallback atomic scatter (only if ws_size is too small for CSR)
// ===========================================================================
__global__ __launch_bounds__(256) void scatter_spmm(
    const int* __restrict__ rows, const int* __restrict__ cols,
    const float* __restrict__ vals, const float* __restrict__ ego,
    float* __restrict__ side, int nnz) {
  long long t = (long long)blockIdx.x * blockDim.x + threadIdx.x;
  int e = (int)(t >> 4);
  if (e >= nnz) return;
  int c4 = (int)(t & 15);
  int r = rows[e];
  int c = cols[e];
  float v = vals[e];
  const float4* src = (const float4*)(ego + (size_t)c * D);
  float4 x = src[c4];
  float* dst = side + (size_t)r * D + c4 * 4;
  atomicAdd(dst + 0, v * x.x);
  atomicAdd(dst + 1, v * x.y);
  atomicAdd(dst + 2, v * x.z);
  atomicAdd(dst + 3, v * x.w);
}

// ===========================================================================
// Per-node transform (unchanged from R1): one wave per node, W in LDS
// ===========================================================================
__global__ __launch_bounds__(256) void transform_nodes(
    float* __restrict__ ego, const float* __restrict__ side,
    const float* __restrict__ Wgc, const float* __restrict__ bgc,
    const float* __restrict__ Wbi, const float* __restrict__ bbi, int N) {
  __shared__ float sWgc[D * D];
  __shared__ float sWbi[D * D];
  __shared__ float sb[2 * D];
  __shared__ float sS[4][D];
  __shared__ float sP[4][D];

  for (int idx = threadIdx.x; idx < D * D; idx += 256) {
    sWgc[idx] = Wgc[idx];
    sWbi[idx] = Wbi[idx];
  }
  if (threadIdx.x < D) {
    sb[threadIdx.x] = bgc[threadIdx.x];
    sb[D + threadIdx.x] = bbi[threadIdx.x];
  }
  __syncthreads();

  int wave = threadIdx.x >> 6;
  int lane = threadIdx.x & 63;
  int waveGlobal = blockIdx.x * 4 + wave;
  int nWaves = gridDim.x * 4;

  for (int n = waveGlobal; n < N; n += nWaves) {
    float s = side[(size_t)n * D + lane];
    float e = ego[(size_t)n * D + lane];
    sS[wave][lane] = s;
    sP[wave][lane] = e * s;
    float accg = sb[lane];
    float accb = sb[D + lane];
#pragma unroll
    for (int i = 0; i < D; i++) {
      float si = sS[wave][i];
      float pi = sP[wave][i];
      accg = fmaf(si, sWgc[i * D + lane], accg);
      accb = fmaf(pi, sWbi[i * D + lane], accb);
    }
    float val = accg + accb;
    val = val > 0.f ? val : NEG_SLOPE * val;
    ego[(size_t)n * D + lane] = val;
  }
}

// ===========================================================================
// Gather one 64-wide slice of the three outputs into d_out
// ===========================================================================
__global__ __launch_bounds__(256) void gather_out(
    const float* __restrict__ ego, const int* __restrict__ u,
    const int* __restrict__ iidx, const int* __restrict__ jidx,
    float* __restrict__ out, int n_users, int B, int slice, int normalize) {
  int r = blockIdx.x * 4 + (threadIdx.x >> 6);
  int lane = threadIdx.x & 63;
  if (r >= 3 * B) return;
  int which = r / B;
  int b = r - which * B;
  int n = (which == 0) ? u[b] : (n_users + ((which == 1) ? iidx[b] : jidx[b]));
  float v = ego[(size_t)n * D + lane];
  if (normalize) {
    float sq = v * v;
#pragma unroll
    for (int off = 32; off > 0; off >>= 1) sq += __shfl_xor(sq, off);
    float norm = sqrtf(sq);
    v = v / fmaxf(norm, EPS);
  }
  out[(size_t)which * B * 256 + (size_t)b * 256 + slice * D + lane] = v;
}

// ===========================================================================
// Launch
// ===========================================================================
extern "C" void kernel_launch(void* const* d_in, const int* in_sizes, int n_in,
                              void* d_out, int out_size, void* d_ws, size_t ws_size,
                              hipStream_t stream) {
  const int*   rows     = (const int*)d_in[0];
  const int*   cols     = (const int*)d_in[1];
  const float* vals     = (const float*)d_in[2];
  const float* user_emb = (const float*)d_in[3];
  const float* item_emb = (const float*)d_in[4];
  const float* W_gc     = (const float*)d_in[5];
  const float* b_gc     = (const float*)d_in[6];
  const float* W_bi     = (const float*)d_in[7];
  const float* b_bi     = (const float*)d_in[8];
  const int*   u        = (const int*)d_in[9];
  const int*   iidx     = (const int*)d_in[10];
  const int*   jidx     = (const int*)d_in[11];

  int nnz     = in_sizes[0];
  int n_users = in_sizes[3] / D;
  int n_items = in_sizes[4] / D;
  int N       = n_users + n_items;
  int B       = in_sizes[9];
  float* out  = (float*)d_out;

  // ---- workspace layout ----
  auto align256 = [](size_t x) { return (x + 255) & ~(size_t)255; };
  char* p = (char*)d_ws;
  float* ego  = (float*)p; p += align256((size_t)N * D * sizeof(float));
  float* side = (float*)p; p += align256((size_t)N * D * sizeof(float));
  int* row_ptr  = (int*)p; p += align256((size_t)(N + 1) * sizeof(int));
  int* cursor   = (int*)p; p += align256((size_t)(N + 1) * sizeof(int));
  int* partials = (int*)p; p += align256(1024 * sizeof(int));
  size_t head = (size_t)(p - (char*)d_ws);
  size_t need_packed = head + (size_t)nnz * sizeof(int2);
  size_t need_eid    = head + (size_t)nnz * sizeof(int);
  int mode = (ws_size >= need_packed) ? 0 : (ws_size >= need_eid ? 1 : 2);
  int2* pairs = (int2*)p;
  int*  eids  = (int*)p;

  // ego = concat(user_emb, item_emb)
  hipMemcpyAsync(ego, user_emb, (size_t)n_users * D * sizeof(float),
                 hipMemcpyDeviceToDevice, stream);
  hipMemcpyAsync(ego + (size_t)n_users * D, item_emb,
                 (size_t)n_items * D * sizeof(float),
                 hipMemcpyDeviceToDevice, stream);

  int eblocks = (nnz + 255) / 256;
  int nblocks_scan = (N + 1023) / 1024;

  if (mode != 2) {
    // ---- CSR build (counting sort) ----
    hipMemsetAsync(cursor, 0, (size_t)N * sizeof(int), stream);  // counts
    hist_rows<<<eblocks, 256, 0, stream>>>(rows, cursor, nnz);
    scan_local<<<nblocks_scan, 256, 0, stream>>>(cursor, row_ptr, partials, N);
    scan_partials<<<1, 256, 0, stream>>>(partials, nblocks_scan);
    add_offsets<<<(N + 255) / 256, 256, 0, stream>>>(row_ptr, partials, N, nnz);
    hipMemcpyAsync(cursor, row_ptr, (size_t)N * sizeof(int),
                   hipMemcpyDeviceToDevice, stream);
    if (mode == 0)
      fill_csr_packed<<<eblocks, 256, 0, stream>>>(rows, cols, vals, cursor,
                                                   pairs, nnz);
    else
      fill_csr_eid<<<eblocks, 256, 0, stream>>>(rows, cursor, eids, nnz);
  }

  // slice 0: raw embeddings
  int gblocks = (3 * B + 3) / 4;
  gather_out<<<gblocks, 256, 0, stream>>>(ego, u, iidx, jidx, out, n_users, B,
                                          0, 0);

  long long sthreads = (long long)nnz * 16;
  int sblocks = (int)((sthreads + 255) / 256);

  for (int k = 0; k < 3; k++) {
    if (mode == 0) {
      spmm_gather_packed<<<2048, 256, 0, stream>>>(row_ptr, pairs, ego, side, N);
    } else if (mode == 1) {
      spmm_gather_eid<<<2048, 256, 0, stream>>>(row_ptr, eids, cols, vals, ego,
                                                side, N);
    } else {
      hipMemsetAsync(side, 0, (size_t)N * D * sizeof(float), stream);
      scatter_spmm<<<sblocks, 256, 0, stream>>>(rows, cols, vals, ego, side,
                                                nnz);
    }
    transform_nodes<<<2048, 256, 0, stream>>>(
        ego, side, W_gc + (size_t)k * D * D, b_gc + (size_t)k * D,
        W_bi + (size_t)k * D * D, b_bi + (size_t)k * D, N);
    gather_out<<<gblocks, 256, 0, stream>>>(ego, u, iidx, jidx, out, n_users,
                                            B, k + 1, 1);
  }
}

// Round 3
// 1871.807 us; speedup vs baseline: 8.9110x; 1.0597x over previous
//
#include <hip/hip_runtime.h>
#include <hip/hip_bf16.h>

#define D 64
#define NEG_SLOPE 0.2f
#define EPS 1e-12f
#define BUCKET_BITS 6            // 64 rows per bucket
#define NB_MAX 4096

// ===========================================================================
// Bucketed CSR build.
// Bucket = row >> 6 (64 rows). Edges are scattered into bucket-contiguous
// storage (cursor-sequential -> only nb open cache lines -> no write
// amplification), then each bucket is counting-sorted by local row.
// ===========================================================================

__global__ __launch_bounds__(256) void bucket_hist(const int* __restrict__ rows,
                                                   int* __restrict__ bcount,
                                                   int nnz, int nb) {
  __shared__ int h[NB_MAX];
  for (int i = threadIdx.x; i < nb; i += 256) h[i] = 0;
  __syncthreads();
  for (int k = blockIdx.x * 256 + threadIdx.x; k < nnz; k += gridDim.x * 256)
    atomicAdd(&h[rows[k] >> BUCKET_BITS], 1);
  __syncthreads();
  for (int i = threadIdx.x; i < nb; i += 256)
    if (h[i]) atomicAdd(&bcount[i], h[i]);
}

// Single block: exclusive scan of nb (<=4096) bucket counts.
// Writes bbase[0..nb] (with bbase[nb]=total), bcursor[i]=bbase[i],
// and row_ptr[N]=nnz.
#define SCAN_E2 16
__global__ __launch_bounds__(256) void scan_buckets(
    const int* __restrict__ bcount, int* __restrict__ bbase,
    int* __restrict__ bcursor, int nb, int nnz, int* __restrict__ row_ptr,
    int N) {
  __shared__ int sums[256];
  int base = threadIdx.x * SCAN_E2;
  int c[SCAN_E2];
  int tsum = 0;
#pragma unroll
  for (int i = 0; i < SCAN_E2; i++) {
    int idx = base + i;
    c[i] = (idx < nb) ? bcount[idx] : 0;
    tsum += c[i];
  }
  sums[threadIdx.x] = tsum;
  __syncthreads();
  for (int off = 1; off < 256; off <<= 1) {
    int t = (threadIdx.x >= off) ? sums[threadIdx.x - off] : 0;
    __syncthreads();
    sums[threadIdx.x] += t;
    __syncthreads();
  }
  int run = sums[threadIdx.x] - tsum;
#pragma unroll
  for (int i = 0; i < SCAN_E2; i++) {
    int idx = base + i;
    if (idx < nb) {
      bbase[idx] = run;
      bcursor[idx] = run;
    }
    run += c[i];
  }
  if (threadIdx.x == 255) {
    bbase[nb] = sums[255];
    row_ptr[N] = nnz;
  }
}

// Scatter edges to bucket-major order. Pack local row (6 bits) into the
// col word: packed = col | (lrow << 20).  Requires N <= 2^20.
__global__ __launch_bounds__(256) void bucket_scatter(
    const int* __restrict__ rows, const int* __restrict__ cols,
    const float* __restrict__ vals, int* __restrict__ bcursor,
    int2* __restrict__ bucketed, int nnz) {
  int k = blockIdx.x * 256 + threadIdx.x;
  if (k >= nnz) return;
  int r = rows[k];
  int pos = atomicAdd(&bcursor[r >> BUCKET_BITS], 1);
  bucketed[pos] = make_int2(cols[k] | ((r & 63) << 20), __float_as_int(vals[k]));
}

// One block per bucket: LDS counting sort of the bucket's edges by local
// row; writes row_ptr for its 64 rows and the final CSR pairs.
__global__ __launch_bounds__(256) void bucket_sort_csr(
    const int2* __restrict__ bucketed, const int* __restrict__ bbase,
    int* __restrict__ row_ptr, int2* __restrict__ pairs, int N) {
  __shared__ int lhist[64], sc[64], lcur[64];
  int b = blockIdx.x;
  int s = bbase[b];
  int e = bbase[b + 1];
  int t = threadIdx.x;
  if (t < 64) lhist[t] = 0;
  __syncthreads();
  for (int k = s + t; k < e; k += 256)
    atomicAdd(&lhist[(unsigned)bucketed[k].x >> 20], 1);
  __syncthreads();
  if (t < 64) sc[t] = lhist[t];
  __syncthreads();
  for (int off = 1; off < 64; off <<= 1) {
    int v = (t < 64 && t >= off) ? sc[t - off] : 0;
    __syncthreads();
    if (t < 64) sc[t] += v;
    __syncthreads();
  }
  if (t < 64) {
    int excl = sc[t] - lhist[t];
    lcur[t] = excl;
    int grow = (b << BUCKET_BITS) + t;
    if (grow < N) row_ptr[grow] = s + excl;
  }
  __syncthreads();
  for (int k = s + t; k < e; k += 256) {
    int2 g = bucketed[k];
    int lr = (unsigned)g.x >> 20;
    int dst = s + atomicAdd(&lcur[lr], 1);
    pairs[dst] = make_int2(g.x & 0xFFFFF, g.y);
  }
}

// ===========================================================================
// SpMM gather: one wave per row, lane = column, register accumulate.
// ===========================================================================
__global__ __launch_bounds__(256) void spmm_gather_packed(
    const int* __restrict__ row_ptr, const int2* __restrict__ pairs,
    const float* __restrict__ ego, float* __restrict__ side, int N) {
  int wave = threadIdx.x >> 6;
  int lane = threadIdx.x & 63;
  int w = blockIdx.x * 4 + wave;
  int stride = gridDim.x * 4;
  for (int n = w; n < N; n += stride) {
    int s = row_ptr[n];
    int e = row_ptr[n + 1];
    float acc = 0.f;
    int k = s;
    for (; k + 3 < e; k += 4) {
      int2 p0 = pairs[k], p1 = pairs[k + 1], p2 = pairs[k + 2], p3 = pairs[k + 3];
      float x0 = ego[(size_t)p0.x * D + lane];
      float x1 = ego[(size_t)p1.x * D + lane];
      float x2 = ego[(size_t)p2.x * D + lane];
      float x3 = ego[(size_t)p3.x * D + lane];
      acc = fmaf(__int_as_float(p0.y), x0, acc);
      acc = fmaf(__int_as_float(p1.y), x1, acc);
      acc = fmaf(__int_as_float(p2.y), x2, acc);
      acc = fmaf(__int_as_float(p3.y), x3, acc);
    }
    for (; k < e; k++) {
      int2 p = pairs[k];
      acc = fmaf(__int_as_float(p.y), ego[(size_t)p.x * D + lane], acc);
    }
    side[(size_t)n * D + lane] = acc;
  }
}

// ===========================================================================
// Fallback atomic scatter (only if ws too small / N too big for CSR path)
// ===========================================================================
__global__ __launch_bounds__(256) void scatter_spmm(
    const int* __restrict__ rows, const int* __restrict__ cols,
    const float* __restrict__ vals, const float* __restrict__ ego,
    float* __restrict__ side, int nnz) {
  long long t = (long long)blockIdx.x * blockDim.x + threadIdx.x;
  int e = (int)(t >> 4);
  if (e >= nnz) return;
  int c4 = (int)(t & 15);
  int r = rows[e];
  int c = cols[e];
  float v = vals[e];
  const float4* src = (const float4*)(ego + (size_t)c * D);
  float4 x = src[c4];
  float* dst = side + (size_t)r * D + c4 * 4;
  atomicAdd(dst + 0, v * x.x);
  atomicAdd(dst + 1, v * x.y);
  atomicAdd(dst + 2, v * x.z);
  atomicAdd(dst + 3, v * x.w);
}

// ===========================================================================
// Per-node transform: one wave per node, W in LDS
// ===========================================================================
__global__ __launch_bounds__(256) void transform_nodes(
    float* __restrict__ ego, const float* __restrict__ side,
    const float* __restrict__ Wgc, const float* __restrict__ bgc,
    const float* __restrict__ Wbi, const float* __restrict__ bbi, int N) {
  __shared__ float sWgc[D * D];
  __shared__ float sWbi[D * D];
  __shared__ float sb[2 * D];
  __shared__ float sS[4][D];
  __shared__ float sP[4][D];

  for (int idx = threadIdx.x; idx < D * D; idx += 256) {
    sWgc[idx] = Wgc[idx];
    sWbi[idx] = Wbi[idx];
  }
  if (threadIdx.x < D) {
    sb[threadIdx.x] = bgc[threadIdx.x];
    sb[D + threadIdx.x] = bbi[threadIdx.x];
  }
  __syncthreads();

  int wave = threadIdx.x >> 6;
  int lane = threadIdx.x & 63;
  int waveGlobal = blockIdx.x * 4 + wave;
  int nWaves = gridDim.x * 4;

  for (int n = waveGlobal; n < N; n += nWaves) {
    float s = side[(size_t)n * D + lane];
    float e = ego[(size_t)n * D + lane];
    sS[wave][lane] = s;
    sP[wave][lane] = e * s;
    float accg = sb[lane];
    float accb = sb[D + lane];
#pragma unroll
    for (int i = 0; i < D; i++) {
      float si = sS[wave][i];
      float pi = sP[wave][i];
      accg = fmaf(si, sWgc[i * D + lane], accg);
      accb = fmaf(pi, sWbi[i * D + lane], accb);
    }
    float val = accg + accb;
    val = val > 0.f ? val : NEG_SLOPE * val;
    ego[(size_t)n * D + lane] = val;
  }
}

// ===========================================================================
// Gather one 64-wide slice of the three outputs into d_out
// ===========================================================================
__global__ __launch_bounds__(256) void gather_out(
    const float* __restrict__ ego, const int* __restrict__ u,
    const int* __restrict__ iidx, const int* __restrict__ jidx,
    float* __restrict__ out, int n_users, int B, int slice, int normalize) {
  int r = blockIdx.x * 4 + (threadIdx.x >> 6);
  int lane = threadIdx.x & 63;
  if (r >= 3 * B) return;
  int which = r / B;
  int b = r - which * B;
  int n = (which == 0) ? u[b] : (n_users + ((which == 1) ? iidx[b] : jidx[b]));
  float v = ego[(size_t)n * D + lane];
  if (normalize) {
    float sq = v * v;
#pragma unroll
    for (int off = 32; off > 0; off >>= 1) sq += __shfl_xor(sq, off);
    float norm = sqrtf(sq);
    v = v / fmaxf(norm, EPS);
  }
  out[(size_t)which * B * 256 + (size_t)b * 256 + slice * D + lane] = v;
}

// ===========================================================================
// Launch
// ===========================================================================
extern "C" void kernel_launch(void* const* d_in, const int* in_sizes, int n_in,
                              void* d_out, int out_size, void* d_ws, size_t ws_size,
                              hipStream_t stream) {
  const int*   rows     = (const int*)d_in[0];
  const int*   cols     = (const int*)d_in[1];
  const float* vals     = (const float*)d_in[2];
  const float* user_emb = (const float*)d_in[3];
  const float* item_emb = (const float*)d_in[4];
  const float* W_gc     = (const float*)d_in[5];
  const float* b_gc     = (const float*)d_in[6];
  const float* W_bi     = (const float*)d_in[7];
  const float* b_bi     = (const float*)d_in[8];
  const int*   u        = (const int*)d_in[9];
  const int*   iidx     = (const int*)d_in[10];
  const int*   jidx     = (const int*)d_in[11];

  int nnz     = in_sizes[0];
  int n_users = in_sizes[3] / D;
  int n_items = in_sizes[4] / D;
  int N       = n_users + n_items;
  int B       = in_sizes[9];
  float* out  = (float*)d_out;

  int nb = (N + 63) >> BUCKET_BITS;

  // ---- workspace layout ----
  auto align256 = [](size_t x) { return (x + 255) & ~(size_t)255; };
  char* p = (char*)d_ws;
  size_t egoBytes  = align256((size_t)N * D * sizeof(float));
  size_t sideBytes = align256((size_t)N * D * sizeof(float));
  if ((size_t)nnz * sizeof(int2) > sideBytes)
    sideBytes = align256((size_t)nnz * sizeof(int2));  // bucketed aliases side

  float* ego  = (float*)p; p += egoBytes;
  float* side = (float*)p;
  int2* bucketed = (int2*)side;  // alias: dead before first spmm use of side
  p += sideBytes;
  int* row_ptr = (int*)p; p += align256((size_t)(N + 1) * sizeof(int));
  int* bcount  = (int*)p; p += align256((size_t)(nb + 1) * sizeof(int));
  int* bbase   = (int*)p; p += align256((size_t)(nb + 1) * sizeof(int));
  int* bcursor = (int*)p; p += align256((size_t)(nb + 1) * sizeof(int));
  int2* pairs  = (int2*)p; p += align256((size_t)nnz * sizeof(int2));
  size_t need = (size_t)(p - (char*)d_ws);

  int mode = (ws_size >= need && N <= (1 << 20) && nb <= NB_MAX) ? 0 : 2;

  // ego = concat(user_emb, item_emb)
  hipMemcpyAsync(ego, user_emb, (size_t)n_users * D * sizeof(float),
                 hipMemcpyDeviceToDevice, stream);
  hipMemcpyAsync(ego + (size_t)n_users * D, item_emb,
                 (size_t)n_items * D * sizeof(float),
                 hipMemcpyDeviceToDevice, stream);

  int eblocks = (nnz + 255) / 256;

  if (mode == 0) {
    hipMemsetAsync(bcount, 0, (size_t)nb * sizeof(int), stream);
    bucket_hist<<<256, 256, 0, stream>>>(rows, bcount, nnz, nb);
    scan_buckets<<<1, 256, 0, stream>>>(bcount, bbase, bcursor, nb, nnz,
                                        row_ptr, N);
    bucket_scatter<<<eblocks, 256, 0, stream>>>(rows, cols, vals, bcursor,
                                                bucketed, nnz);
    bucket_sort_csr<<<nb, 256, 0, stream>>>(bucketed, bbase, row_ptr, pairs, N);
  }

  // slice 0: raw embeddings
  int gblocks = (3 * B + 3) / 4;
  gather_out<<<gblocks, 256, 0, stream>>>(ego, u, iidx, jidx, out, n_users, B,
                                          0, 0);

  long long sthreads = (long long)nnz * 16;
  int sblocks = (int)((sthreads + 255) / 256);

  for (int k = 0; k < 3; k++) {
    if (mode == 0) {
      spmm_gather_packed<<<2048, 256, 0, stream>>>(row_ptr, pairs, ego, side, N);
    } else {
      hipMemsetAsync(side, 0, (size_t)N * D * sizeof(float), stream);
      scatter_spmm<<<sblocks, 256, 0, stream>>>(rows, cols, vals, ego, side,
                                                nnz);
    }
    transform_nodes<<<2048, 256, 0, stream>>>(
        ego, side, W_gc + (size_t)k * D * D, b_gc + (size_t)k * D,
        W_bi + (size_t)k * D * D, b_bi + (size_t)k * D, N);
    gather_out<<<gblocks, 256, 0, stream>>>(ego, u, iidx, jidx, out, n_users,
                                            B, k + 1, 1);
  }
}

// Round 4
// 1435.194 us; speedup vs baseline: 11.6219x; 1.3042x over previous
//
#include <hip/hip_runtime.h>
#include <hip/hip_bf16.h>

#define D 64
#define NEG_SLOPE 0.2f
#define EPS 1e-12f
#define CB 9                 // coarse bucket bits: 512 rows per bucket
#define CROWS (1 << CB)
#define NBC_MAX 1024         // supports N <= 524288
#define TILE_E 8192

__device__ __forceinline__ unsigned short f32_to_bf16(float f) {
  unsigned b = __float_as_uint(f);
  return (unsigned short)((b + 0x7FFF + ((b >> 16) & 1)) >> 16);
}

// ===========================================================================
// CSR build, write-amp-free: tile-ranked scatter into coarse buckets,
// then per-bucket counting sort by local row.
// ===========================================================================

__global__ __launch_bounds__(256) void hist_coarse(const int* __restrict__ rows,
                                                   int* __restrict__ bcount,
                                                   int nnz, int nbc) {
  __shared__ int h[NBC_MAX];
  for (int i = threadIdx.x; i < nbc; i += 256) h[i] = 0;
  __syncthreads();
  for (int k = blockIdx.x * 256 + threadIdx.x; k < nnz; k += gridDim.x * 256)
    atomicAdd(&h[rows[k] >> CB], 1);
  __syncthreads();
  for (int i = threadIdx.x; i < nbc; i += 256)
    if (h[i]) atomicAdd(&bcount[i], h[i]);
}

// Single block: exclusive scan of nbc (<=1024) counts -> bbase, bcursor.
#define SCAN_E2 4
__global__ __launch_bounds__(256) void scan_buckets(
    const int* __restrict__ bcount, int* __restrict__ bbase,
    int* __restrict__ bcursor, int nbc, int nnz, int* __restrict__ row_ptr,
    int N) {
  __shared__ int sums[256];
  int base = threadIdx.x * SCAN_E2;
  int c[SCAN_E2];
  int tsum = 0;
#pragma unroll
  for (int i = 0; i < SCAN_E2; i++) {
    int idx = base + i;
    c[i] = (idx < nbc) ? bcount[idx] : 0;
    tsum += c[i];
  }
  sums[threadIdx.x] = tsum;
  __syncthreads();
  for (int off = 1; off < 256; off <<= 1) {
    int t = (threadIdx.x >= off) ? sums[threadIdx.x - off] : 0;
    __syncthreads();
    sums[threadIdx.x] += t;
    __syncthreads();
  }
  int run = sums[threadIdx.x] - tsum;
#pragma unroll
  for (int i = 0; i < SCAN_E2; i++) {
    int idx = base + i;
    if (idx < nbc) {
      bbase[idx] = run;
      bcursor[idx] = run;
    }
    run += c[i];
  }
  if (threadIdx.x == 255) {
    bbase[nbc] = sums[255];
    row_ptr[N] = nnz;
  }
}

// Per-tile: LDS hist -> one global claim per (tile,bucket) -> ranked write.
// Each bucket gets block-contiguous runs => cache lines complete within one
// XCD's L2 => no write amplification.
__global__ __launch_bounds__(256) void scatter_ranked(
    const int* __restrict__ rows, const int* __restrict__ cols,
    const float* __restrict__ vals, int* __restrict__ bcursor,
    int2* __restrict__ bucketed, int nnz, int nbc) {
  __shared__ int h[NBC_MAX];
  int ntiles = (nnz + TILE_E - 1) / TILE_E;
  for (int tile = blockIdx.x; tile < ntiles; tile += gridDim.x) {
    int s = tile * TILE_E;
    int e = min(s + TILE_E, nnz);
    for (int i = threadIdx.x; i < nbc; i += 256) h[i] = 0;
    __syncthreads();
    for (int k = s + threadIdx.x; k < e; k += 256)
      atomicAdd(&h[rows[k] >> CB], 1);
    __syncthreads();
    for (int i = threadIdx.x; i < nbc; i += 256) {
      int c = h[i];
      h[i] = c ? atomicAdd(&bcursor[i], c) : 0;
    }
    __syncthreads();
    for (int k = s + threadIdx.x; k < e; k += 256) {
      int r = rows[k];
      int pos = atomicAdd(&h[r >> CB], 1);
      bucketed[pos] =
          make_int2(cols[k] | ((r & (CROWS - 1)) << 20), __float_as_int(vals[k]));
    }
    __syncthreads();
  }
}

// One block per coarse bucket: counting sort by local row (512 counters).
__global__ __launch_bounds__(256) void sort_csr(
    const int2* __restrict__ bucketed, const int* __restrict__ bbase,
    int* __restrict__ row_ptr, int2* __restrict__ pairs, int N) {
  __shared__ int lhist[CROWS];
  __shared__ int sums[256];
  int b = blockIdx.x;
  int s = bbase[b];
  int e = bbase[b + 1];
  int t = threadIdx.x;
  for (int i = t; i < CROWS; i += 256) lhist[i] = 0;
  __syncthreads();
  for (int k = s + t; k < e; k += 256)
    atomicAdd(&lhist[(unsigned)bucketed[k].x >> 20], 1);
  __syncthreads();
  int c0 = lhist[2 * t];
  int c1 = lhist[2 * t + 1];
  int tsum = c0 + c1;
  sums[t] = tsum;
  __syncthreads();
  for (int off = 1; off < 256; off <<= 1) {
    int v = (t >= off) ? sums[t - off] : 0;
    __syncthreads();
    sums[t] += v;
    __syncthreads();
  }
  int run = sums[t] - tsum;
  int base0 = s + run;
  int base1 = base0 + c0;
  lhist[2 * t] = base0;
  lhist[2 * t + 1] = base1;
  int grow = (b << CB) + 2 * t;
  if (grow < N) row_ptr[grow] = base0;
  if (grow + 1 < N) row_ptr[grow + 1] = base1;
  __syncthreads();
  for (int k = s + t; k < e; k += 256) {
    int2 g = bucketed[k];
    int lr = (unsigned)g.x >> 20;
    int dst = atomicAdd(&lhist[lr], 1);
    pairs[dst] = make_int2(g.x & 0xFFFFF, g.y);
  }
}

// ===========================================================================
// ego -> bf16 mirror (RTNE)
// ===========================================================================
__global__ __launch_bounds__(256) void cvt_ego16(const float* __restrict__ ego,
                                                 unsigned short* __restrict__ ego16,
                                                 int n4) {
  int i = blockIdx.x * 256 + threadIdx.x;
  if (i >= n4) return;
  float4 v = ((const float4*)ego)[i];
  ushort4 o;
  o.x = f32_to_bf16(v.x);
  o.y = f32_to_bf16(v.y);
  o.z = f32_to_bf16(v.z);
  o.w = f32_to_bf16(v.w);
  ((ushort4*)ego16)[i] = o;
}

// ===========================================================================
// SpMM gather: one wave per row, lane = column, register accumulate.
// ===========================================================================
__global__ __launch_bounds__(256) void spmm_gather_bf16(
    const int* __restrict__ row_ptr, const int2* __restrict__ pairs,
    const unsigned short* __restrict__ ego16, float* __restrict__ side, int N) {
  int wave = threadIdx.x >> 6;
  int lane = threadIdx.x & 63;
  int w = blockIdx.x * 4 + wave;
  int stride = gridDim.x * 4;
  for (int n = w; n < N; n += stride) {
    int s = row_ptr[n];
    int e = row_ptr[n + 1];
    float acc = 0.f;
    int k = s;
    for (; k + 3 < e; k += 4) {
      int2 p0 = pairs[k], p1 = pairs[k + 1], p2 = pairs[k + 2], p3 = pairs[k + 3];
      float x0 = __uint_as_float((unsigned)ego16[(size_t)p0.x * D + lane] << 16);
      float x1 = __uint_as_float((unsigned)ego16[(size_t)p1.x * D + lane] << 16);
      float x2 = __uint_as_float((unsigned)ego16[(size_t)p2.x * D + lane] << 16);
      float x3 = __uint_as_float((unsigned)ego16[(size_t)p3.x * D + lane] << 16);
      acc = fmaf(__int_as_float(p0.y), x0, acc);
      acc = fmaf(__int_as_float(p1.y), x1, acc);
      acc = fmaf(__int_as_float(p2.y), x2, acc);
      acc = fmaf(__int_as_float(p3.y), x3, acc);
    }
    for (; k < e; k++) {
      int2 p = pairs[k];
      float x = __uint_as_float((unsigned)ego16[(size_t)p.x * D + lane] << 16);
      acc = fmaf(__int_as_float(p.y), x, acc);
    }
    side[(size_t)n * D + lane] = acc;
  }
}

__global__ __launch_bounds__(256) void spmm_gather_packed(
    const int* __restrict__ row_ptr, const int2* __restrict__ pairs,
    const float* __restrict__ ego, float* __restrict__ side, int N) {
  int wave = threadIdx.x >> 6;
  int lane = threadIdx.x & 63;
  int w = blockIdx.x * 4 + wave;
  int stride = gridDim.x * 4;
  for (int n = w; n < N; n += stride) {
    int s = row_ptr[n];
    int e = row_ptr[n + 1];
    float acc = 0.f;
    int k = s;
    for (; k + 3 < e; k += 4) {
      int2 p0 = pairs[k], p1 = pairs[k + 1], p2 = pairs[k + 2], p3 = pairs[k + 3];
      float x0 = ego[(size_t)p0.x * D + lane];
      float x1 = ego[(size_t)p1.x * D + lane];
      float x2 = ego[(size_t)p2.x * D + lane];
      float x3 = ego[(size_t)p3.x * D + lane];
      acc = fmaf(__int_as_float(p0.y), x0, acc);
      acc = fmaf(__int_as_float(p1.y), x1, acc);
      acc = fmaf(__int_as_float(p2.y), x2, acc);
      acc = fmaf(__int_as_float(p3.y), x3, acc);
    }
    for (; k < e; k++) {
      int2 p = pairs[k];
      acc = fmaf(__int_as_float(p.y), ego[(size_t)p.x * D + lane], acc);
    }
    side[(size_t)n * D + lane] = acc;
  }
}

// ===========================================================================
// Fallback atomic scatter (only if ws too small / N too big for CSR path)
// ===========================================================================
__global__ __launch_bounds__(256) void scatter_spmm(
    const int* __restrict__ rows, const int* __restrict__ cols,
    const float* __restrict__ vals, const float* __restrict__ ego,
    float* __restrict__ side, int nnz) {
  long long t = (long long)blockIdx.x * blockDim.x + threadIdx.x;
  int e = (int)(t >> 4);
  if (e >= nnz) return;
  int c4 = (int)(t & 15);
  int r = rows[e];
  int c = cols[e];
  float v = vals[e];
  const float4* src = (const float4*)(ego + (size_t)c * D);
  float4 x = src[c4];
  float* dst = side + (size_t)r * D + c4 * 4;
  atomicAdd(dst + 0, v * x.x);
  atomicAdd(dst + 1, v * x.y);
  atomicAdd(dst + 2, v * x.z);
  atomicAdd(dst + 3, v * x.w);
}

// ===========================================================================
// Per-node transform: one wave per node, W in LDS. Optionally mirrors the
// new ego into bf16 for the next layer's SpMM gather.
// ===========================================================================
__global__ __launch_bounds__(256) void transform_nodes(
    float* __restrict__ ego, const float* __restrict__ side,
    const float* __restrict__ Wgc, const float* __restrict__ bgc,
    const float* __restrict__ Wbi, const float* __restrict__ bbi,
    unsigned short* __restrict__ ego16, int w16, int N) {
  __shared__ float sWgc[D * D];
  __shared__ float sWbi[D * D];
  __shared__ float sb[2 * D];
  __shared__ float sS[4][D];
  __shared__ float sP[4][D];

  for (int idx = threadIdx.x; idx < D * D; idx += 256) {
    sWgc[idx] = Wgc[idx];
    sWbi[idx] = Wbi[idx];
  }
  if (threadIdx.x < D) {
    sb[threadIdx.x] = bgc[threadIdx.x];
    sb[D + threadIdx.x] = bbi[threadIdx.x];
  }
  __syncthreads();

  int wave = threadIdx.x >> 6;
  int lane = threadIdx.x & 63;
  int waveGlobal = blockIdx.x * 4 + wave;
  int nWaves = gridDim.x * 4;

  for (int n = waveGlobal; n < N; n += nWaves) {
    float s = side[(size_t)n * D + lane];
    float e = ego[(size_t)n * D + lane];
    sS[wave][lane] = s;
    sP[wave][lane] = e * s;
    float accg = sb[lane];
    float accb = sb[D + lane];
#pragma unroll
    for (int i = 0; i < D; i++) {
      float si = sS[wave][i];
      float pi = sP[wave][i];
      accg = fmaf(si, sWgc[i * D + lane], accg);
      accb = fmaf(pi, sWbi[i * D + lane], accb);
    }
    float val = accg + accb;
    val = val > 0.f ? val : NEG_SLOPE * val;
    ego[(size_t)n * D + lane] = val;
    if (w16) ego16[(size_t)n * D + lane] = f32_to_bf16(val);
  }
}

// ===========================================================================
// Gather one 64-wide slice of the three outputs into d_out
// ===========================================================================
__global__ __launch_bounds__(256) void gather_out(
    const float* __restrict__ ego, const int* __restrict__ u,
    const int* __restrict__ iidx, const int* __restrict__ jidx,
    float* __restrict__ out, int n_users, int B, int slice, int normalize) {
  int r = blockIdx.x * 4 + (threadIdx.x >> 6);
  int lane = threadIdx.x & 63;
  if (r >= 3 * B) return;
  int which = r / B;
  int b = r - which * B;
  int n = (which == 0) ? u[b] : (n_users + ((which == 1) ? iidx[b] : jidx[b]));
  float v = ego[(size_t)n * D + lane];
  if (normalize) {
    float sq = v * v;
#pragma unroll
    for (int off = 32; off > 0; off >>= 1) sq += __shfl_xor(sq, off);
    float norm = sqrtf(sq);
    v = v / fmaxf(norm, EPS);
  }
  out[(size_t)which * B * 256 + (size_t)b * 256 + slice * D + lane] = v;
}

// ===========================================================================
// Launch
// ===========================================================================
extern "C" void kernel_launch(void* const* d_in, const int* in_sizes, int n_in,
                              void* d_out, int out_size, void* d_ws, size_t ws_size,
                              hipStream_t stream) {
  const int*   rows     = (const int*)d_in[0];
  const int*   cols     = (const int*)d_in[1];
  const float* vals     = (const float*)d_in[2];
  const float* user_emb = (const float*)d_in[3];
  const float* item_emb = (const float*)d_in[4];
  const float* W_gc     = (const float*)d_in[5];
  const float* b_gc     = (const float*)d_in[6];
  const float* W_bi     = (const float*)d_in[7];
  const float* b_bi     = (const float*)d_in[8];
  const int*   u        = (const int*)d_in[9];
  const int*   iidx     = (const int*)d_in[10];
  const int*   jidx     = (const int*)d_in[11];

  int nnz     = in_sizes[0];
  int n_users = in_sizes[3] / D;
  int n_items = in_sizes[4] / D;
  int N       = n_users + n_items;
  int B       = in_sizes[9];
  float* out  = (float*)d_out;

  int nbc = (N + CROWS - 1) >> CB;

  // ---- workspace layout ----
  auto align256 = [](size_t x) { return (x + 255) & ~(size_t)255; };
  char* p = (char*)d_ws;
  size_t egoBytes  = align256((size_t)N * D * sizeof(float));
  size_t sideBytes = align256((size_t)N * D * sizeof(float));
  if ((size_t)nnz * sizeof(int2) > sideBytes)
    sideBytes = align256((size_t)nnz * sizeof(int2));  // bucketed aliases side

  float* ego  = (float*)p; p += egoBytes;
  float* side = (float*)p;
  int2* bucketed = (int2*)side;  // alias: dead before first spmm use of side
  p += sideBytes;
  int* row_ptr = (int*)p; p += align256((size_t)(N + 1) * sizeof(int));
  int* bcount  = (int*)p; p += align256((size_t)(nbc + 1) * sizeof(int));
  int* bbase   = (int*)p; p += align256((size_t)(nbc + 1) * sizeof(int));
  int* bcursor = (int*)p; p += align256((size_t)(nbc + 1) * sizeof(int));
  int2* pairs  = (int2*)p; p += align256((size_t)nnz * sizeof(int2));
  size_t need_csr = (size_t)(p - (char*)d_ws);
  unsigned short* ego16 = (unsigned short*)p;
  p += align256((size_t)N * D * sizeof(unsigned short));
  size_t need_16 = (size_t)(p - (char*)d_ws);

  int mode  = (ws_size >= need_csr && N <= (1 << 20) && nbc <= NBC_MAX) ? 0 : 2;
  int use16 = (mode == 0 && ws_size >= need_16) ? 1 : 0;

  // ego = concat(user_emb, item_emb)
  hipMemcpyAsync(ego, user_emb, (size_t)n_users * D * sizeof(float),
                 hipMemcpyDeviceToDevice, stream);
  hipMemcpyAsync(ego + (size_t)n_users * D, item_emb,
                 (size_t)n_items * D * sizeof(float),
                 hipMemcpyDeviceToDevice, stream);

  if (mode == 0) {
    if (use16) {
      int n4 = N * D / 4;
      cvt_ego16<<<(n4 + 255) / 256, 256, 0, stream>>>(ego, ego16, n4);
    }
    hipMemsetAsync(bcount, 0, (size_t)nbc * sizeof(int), stream);
    hist_coarse<<<256, 256, 0, stream>>>(rows, bcount, nnz, nbc);
    scan_buckets<<<1, 256, 0, stream>>>(bcount, bbase, bcursor, nbc, nnz,
                                        row_ptr, N);
    int ntiles = (nnz + TILE_E - 1) / TILE_E;
    scatter_ranked<<<ntiles, 256, 0, stream>>>(rows, cols, vals, bcursor,
                                               bucketed, nnz, nbc);
    sort_csr<<<nbc, 256, 0, stream>>>(bucketed, bbase, row_ptr, pairs, N);
  }

  // slice 0: raw embeddings
  int gblocks = (3 * B + 3) / 4;
  gather_out<<<gblocks, 256, 0, stream>>>(ego, u, iidx, jidx, out, n_users, B,
                                          0, 0);

  long long sthreads = (long long)nnz * 16;
  int sblocks = (int)((sthreads + 255) / 256);

  for (int k = 0; k < 3; k++) {
    if (mode == 0) {
      if (use16)
        spmm_gather_bf16<<<2048, 256, 0, stream>>>(row_ptr, pairs, ego16, side,
                                                   N);
      else
        spmm_gather_packed<<<2048, 256, 0, stream>>>(row_ptr, pairs, ego, side,
                                                     N);
    } else {
      hipMemsetAsync(side, 0, (size_t)N * D * sizeof(float), stream);
      scatter_spmm<<<sblocks, 256, 0, stream>>>(rows, cols, vals, ego, side,
                                                nnz);
    }
    transform_nodes<<<2048, 256, 0, stream>>>(
        ego, side, W_gc + (size_t)k * D * D, b_gc + (size_t)k * D,
        W_bi + (size_t)k * D * D, b_bi + (size_t)k * D, ego16, use16, N);
    gather_out<<<gblocks, 256, 0, stream>>>(ego, u, iidx, jidx, out, n_users,
                                            B, k + 1, 1);
  }
}